// Round 2
// baseline (544.040 us; speedup 1.0000x reference)
//
#include <hip/hip_runtime.h>
#include <stdint.h>

#define NROWS 2048
#define NCOLS 50257
#define SCALE 30.0f

// One block per row. Sum exp(30*x) over the row, compute the per-row loss
// term L_i, and atomically accumulate -L_i/NROWS into out[0].
// out[0] is zeroed by a hipMemsetAsync before this kernel.
__global__ __launch_bounds__(256) void amsoftmax_fused_kernel(
    const float* __restrict__ score,
    const int* __restrict__ labels,
    float* __restrict__ out) {
    const int row = blockIdx.x;
    const int tid = threadIdx.x;
    const float* __restrict__ r = score + (size_t)row * NCOLS;

    const int lab = labels[row];
    const float target = r[lab];
    const float margin = lab ? 0.4f : 0.1f;
    const float num = SCALE * (target - margin);

    // Row base is only 4B-aligned (NCOLS odd). Peel to 16B alignment, then float4.
    const uintptr_t addr = (uintptr_t)r;
    const int mis = (int)(((16u - (addr & 15u)) & 15u) >> 2);  // leading scalars

    float acc0 = 0.0f, acc1 = 0.0f;
    for (int j = tid; j < mis; j += 256) {
        acc0 += __expf(SCALE * r[j]);
    }
    const int nvec = (NCOLS - mis) >> 2;
    const float4* __restrict__ rv = (const float4*)(r + mis);

    // Unroll x2 with independent accumulators: 2 dwordx4 loads in flight per
    // wave per iteration -> better MLP for latency hiding.
    int j = tid;
    for (; j + 256 < nvec; j += 512) {
        float4 v0 = rv[j];
        float4 v1 = rv[j + 256];
        acc0 += __expf(SCALE * v0.x);
        acc0 += __expf(SCALE * v0.y);
        acc0 += __expf(SCALE * v0.z);
        acc0 += __expf(SCALE * v0.w);
        acc1 += __expf(SCALE * v1.x);
        acc1 += __expf(SCALE * v1.y);
        acc1 += __expf(SCALE * v1.z);
        acc1 += __expf(SCALE * v1.w);
    }
    for (; j < nvec; j += 256) {
        float4 v = rv[j];
        acc0 += __expf(SCALE * v.x);
        acc0 += __expf(SCALE * v.y);
        acc0 += __expf(SCALE * v.z);
        acc0 += __expf(SCALE * v.w);
    }
    for (int k = mis + (nvec << 2) + tid; k < NCOLS; k += 256) {
        acc1 += __expf(SCALE * r[k]);
    }

    float acc = acc0 + acc1;
    // Wave (64-lane) butterfly reduce, then LDS across the 4 waves.
    for (int off = 32; off > 0; off >>= 1) acc += __shfl_down(acc, off);
    __shared__ float wsum[4];
    if ((tid & 63) == 0) wsum[tid >> 6] = acc;
    __syncthreads();
    if (tid == 0) {
        const float total = wsum[0] + wsum[1] + wsum[2] + wsum[3];
        const float excl = total - __expf(SCALE * target);
        const float denom = __expf(num) + excl;
        const float L = num - __logf(denom);
        atomicAdd(out, -L * (1.0f / (float)NROWS));
    }
}

extern "C" void kernel_launch(void* const* d_in, const int* in_sizes, int n_in,
                              void* d_out, int out_size, void* d_ws, size_t ws_size,
                              hipStream_t stream) {
    const float* score = (const float*)d_in[0];
    const int* labels = (const int*)d_in[1];
    float* out = (float*)d_out;

    hipMemsetAsync(out, 0, sizeof(float), stream);
    amsoftmax_fused_kernel<<<NROWS, 256, 0, stream>>>(score, labels, out);
}

// Round 4
// 504.675 us; speedup vs baseline: 1.0780x; 1.0780x over previous
//
#include <hip/hip_runtime.h>
#include <stdint.h>

#define NROWS 2048
#define NCOLS 50257
#define SCALE 30.0f
// SCALE * log2(e): exp(30*x) == exp2(K2*x)
#define K2 43.28085122666891f

typedef float v4f __attribute__((ext_vector_type(4)));

static __device__ __forceinline__ v4f nt_load4(const float* p) {
    return __builtin_nontemporal_load((const v4f*)p);
}

// v_exp_f32 computes 2^x. Avoid __exp2f (glibc macro collision in this TU).
static __device__ __forceinline__ float fexp2(float x) {
    return __builtin_amdgcn_exp2f(x);
}

// One block per row. Sum exp2(K2*x) over the row, compute the per-row loss
// term L_i, atomically accumulate -L_i/NROWS into out[0] (zeroed by memset).
__global__ __launch_bounds__(256) void amsoftmax_fused_kernel(
    const float* __restrict__ score,
    const int* __restrict__ labels,
    float* __restrict__ out) {
    const int row = blockIdx.x;
    const int tid = threadIdx.x;
    const float* __restrict__ r = score + (size_t)row * NCOLS;

    const int lab = labels[row];
    const float target = r[lab];
    const float margin = lab ? 0.4f : 0.1f;
    const float num = SCALE * (target - margin);

    // Row base is only 4B-aligned (NCOLS odd). Peel to 16B alignment.
    const uintptr_t addr = (uintptr_t)r;
    const int mis = (int)(((16u - (addr & 15u)) & 15u) >> 2);

    float a0 = 0.0f, a1 = 0.0f, a2 = 0.0f, a3 = 0.0f;
    for (int j = tid; j < mis; j += 256) a0 += fexp2(K2 * r[j]);

    const int nvec = (NCOLS - mis) >> 2;
    const float* __restrict__ rb = r + mis;

    // x4 unroll, 4 independent dwordx4 nontemporal loads in flight per wave.
    int j = tid;
    for (; j + 768 < nvec; j += 1024) {
        v4f v0 = nt_load4(rb + 4 * (size_t)j);
        v4f v1 = nt_load4(rb + 4 * (size_t)(j + 256));
        v4f v2 = nt_load4(rb + 4 * (size_t)(j + 512));
        v4f v3 = nt_load4(rb + 4 * (size_t)(j + 768));
        a0 += fexp2(K2 * v0.x) + fexp2(K2 * v0.y) +
              fexp2(K2 * v0.z) + fexp2(K2 * v0.w);
        a1 += fexp2(K2 * v1.x) + fexp2(K2 * v1.y) +
              fexp2(K2 * v1.z) + fexp2(K2 * v1.w);
        a2 += fexp2(K2 * v2.x) + fexp2(K2 * v2.y) +
              fexp2(K2 * v2.z) + fexp2(K2 * v2.w);
        a3 += fexp2(K2 * v3.x) + fexp2(K2 * v3.y) +
              fexp2(K2 * v3.z) + fexp2(K2 * v3.w);
    }
    for (; j < nvec; j += 256) {
        v4f v = nt_load4(rb + 4 * (size_t)j);
        a0 += fexp2(K2 * v.x) + fexp2(K2 * v.y) +
              fexp2(K2 * v.z) + fexp2(K2 * v.w);
    }
    for (int k = mis + (nvec << 2) + tid; k < NCOLS; k += 256) {
        a1 += fexp2(K2 * r[k]);
    }

    float acc = (a0 + a1) + (a2 + a3);
    for (int off = 32; off > 0; off >>= 1) acc += __shfl_down(acc, off);
    __shared__ float wsum[4];
    if ((tid & 63) == 0) wsum[tid >> 6] = acc;
    __syncthreads();
    if (tid == 0) {
        const float total = wsum[0] + wsum[1] + wsum[2] + wsum[3];
        const float excl = total - fexp2(K2 * target);
        const float denom = __expf(num) + excl;
        const float L = num - __logf(denom);
        atomicAdd(out, -L * (1.0f / (float)NROWS));
    }
}

extern "C" void kernel_launch(void* const* d_in, const int* in_sizes, int n_in,
                              void* d_out, int out_size, void* d_ws, size_t ws_size,
                              hipStream_t stream) {
    const float* score = (const float*)d_in[0];
    const int* labels = (const int*)d_in[1];
    float* out = (float*)d_out;

    hipMemsetAsync(out, 0, sizeof(float), stream);
    amsoftmax_fused_kernel<<<NROWS, 256, 0, stream>>>(score, labels, out);
}